// Round 5
// baseline (803.479 us; speedup 1.0000x reference)
//
#include <hip/hip_runtime.h>

#define P 16384
#define S 4096
#define NB 8
#define CAP 12

typedef unsigned long long u64;
typedef unsigned int u32;

// Opaque identity: forces the value to be materialized (separate rounding),
// blocking fma contraction across it. Zero instructions emitted.
#define OPAQUE(x) __asm__("" : "+v"(x))

// Rank key: reference computes pd = -xx - inner - xx2 (f32) and takes top_k
// (largest pd first, ties -> lower index). Map pd to u32 dk monotone
// DESCENDING in pd, pack (dk<<32)|idx; ascending u64 order then reproduces
// jax.lax.top_k order exactly.
__device__ __forceinline__ u32 pd_to_dk(float pd) {
  pd = pd + 0.0f;                        // canonicalize -0 -> +0
  u32 b = __float_as_uint(pd);
  u32 s = (u32)((int)b >> 31);           // 0xFFFFFFFF if negative else 0
  return b ^ (~(s | 0x80000000u));       // neg: b ; non-neg: b ^ 0x7FFFFFFF
}

__device__ __forceinline__ void insert16(u64 (&L)[16], u64 key) {
#pragma unroll
  for (int j = 15; j >= 1; --j) {
    u64 a = (L[j - 1] > key) ? L[j - 1] : key;
    L[j] = (L[j] > key) ? a : L[j];
  }
  L[0] = (L[0] > key) ? key : L[0];
}

// ---------------- Kernel A: per-batch min/max of channels 0,1 ----------------
__global__ void kminmax(const float* __restrict__ x, float* __restrict__ mm) {
  int b = blockIdx.x;
  int tid = threadIdx.x;
  const float* x0 = x + (size_t)b * 5 * P;
  const float* x1 = x0 + P;
  float mn0 = __builtin_inff(), mx0 = -__builtin_inff();
  float mn1 = __builtin_inff(), mx1 = -__builtin_inff();
  for (int i = tid; i < P; i += 256) {
    float a = x0[i];
    mn0 = fminf(mn0, a); mx0 = fmaxf(mx0, a);
    float c = x1[i];
    mn1 = fminf(mn1, c); mx1 = fmaxf(mx1, c);
  }
  __shared__ float s0[256], s1[256], s2[256], s3[256];
  s0[tid] = mn0; s1[tid] = mx0; s2[tid] = mn1; s3[tid] = mx1;
  __syncthreads();
  for (int off = 128; off > 0; off >>= 1) {
    if (tid < off) {
      s0[tid] = fminf(s0[tid], s0[tid + off]);
      s1[tid] = fmaxf(s1[tid], s1[tid + off]);
      s2[tid] = fminf(s2[tid], s2[tid + off]);
      s3[tid] = fmaxf(s3[tid], s3[tid + off]);
    }
    __syncthreads();
  }
  if (tid == 0) {
    mm[b * 4 + 0] = s0[0];
    mm[b * 4 + 1] = s1[0];
    mm[b * 4 + 2] = s2[0];
    mm[b * 4 + 3] = s3[0];
  }
}

// ---------------- Kernel B: 1-NN in 2D, reference-faithful roundings --------
// xx, xx2: mul then separate add (reduce HLO, no fma). ip: GEMM fma chain.
// pd: ((-xx) - inner) - xx2, separate subs.
__global__ __launch_bounds__(256) void kidx1(const float* __restrict__ x,
                                             const float* __restrict__ mm,
                                             float* __restrict__ qx,
                                             float* __restrict__ qy,
                                             float* __restrict__ qz) {
#pragma clang fp contract(off)
  int b = blockIdx.x >> 6, sgrp = blockIdx.x & 63;
  int w = threadIdx.x >> 6, l = threadIdx.x & 63;
  const float* xs = x + (size_t)b * 5 * P;
  const float* ys = xs + P;
  float mn0 = mm[b * 4 + 0], mx0 = mm[b * 4 + 1];
  float mn1 = mm[b * 4 + 2], mx1 = mm[b * 4 + 3];
  // s = sgrp*64 + l ; mesh ch0 = (s%64)/64 = l/64 ; ch1 = (s/64)/64 = sgrp/64
  float m0 = (float)l * (1.0f / 64.0f);
  float m1 = (float)sgrp * (1.0f / 64.0f);
  // point_sample = mesh*(max-min)+min : sub, mul, add all separately rounded
  float d0 = mx0 - mn0, d1 = mx1 - mn1;
  float p0 = m0 * d0; OPAQUE(p0);
  float q0 = p0 + mn0;
  float p1 = m1 * d1; OPAQUE(p1);
  float q1 = p1 + mn1;
  // xx2 = q0^2 + q1^2 : muls separately rounded, then add (no fma)
  float sq0 = q0 * q0; OPAQUE(sq0);
  float sq1 = q1 * q1; OPAQUE(sq1);
  float qq = sq0 + sq1;

  int base = w * 4096;
  const float4* xs4 = (const float4*)(xs + base);
  const float4* ys4 = (const float4*)(ys + base);
  u64 best = ~0ULL;
  for (int j = 0; j < 1024; ++j) {
    float4 cx = xs4[j];
    float4 cy = ys4[j];
    float cxa[4] = {cx.x, cx.y, cx.z, cx.w};
    float cya[4] = {cy.x, cy.y, cy.z, cy.w};
#pragma unroll
    for (int t = 0; t < 4; ++t) {
      // xx = x0^2 + x1^2 (no fma)
      float t0 = cxa[t] * cxa[t]; OPAQUE(t0);
      float t1 = cya[t] * cya[t]; OPAQUE(t1);
      float xxp = t0 + t1;
      // ip = fma(x1,q1, round(x0*q0))  (GEMM K=2 fma chain, acc from 0)
      float ip = __builtin_fmaf(cya[t], q1, cxa[t] * q0);
      float inner = -2.0f * ip; OPAQUE(inner);
      float pd = (-xxp - inner) - qq;
      u64 key = ((u64)pd_to_dk(pd) << 32) | (u32)(base + (j << 2) + t);
      best = (key < best) ? key : best;
    }
  }
  __shared__ u64 kb[4][64];
  kb[w][l] = best;
  __syncthreads();
  if (threadIdx.x < 64) {
    u64 m = kb[0][l];
    u64 t1 = kb[1][l]; m = (t1 < m) ? t1 : m;
    u64 t2 = kb[2][l]; m = (t2 < m) ? t2 : m;
    u64 t3 = kb[3][l]; m = (t3 < m) ? t3 : m;
    u32 idx = (u32)m;
    int qi = (b << 12) + (sgrp << 6) + l;
    qx[qi] = xs[idx];
    qy[qi] = ys[idx];
    qz[qi] = xs[2 * P + idx];
  }
}

// ---------------- Kernel C: 16-NN in 3D, reference-faithful + gather --------
__global__ __launch_bounds__(256) void kidx2(const float* __restrict__ x,
                                             const float* __restrict__ qx,
                                             const float* __restrict__ qy,
                                             const float* __restrict__ qz,
                                             float* __restrict__ out) {
#pragma clang fp contract(off)
  __shared__ u64 lists[4][64][16];   // 32 KB
  __shared__ u64 buf[256][CAP];      // 24 KB (reused post-scan for merged keys)
  int b = blockIdx.x >> 6, sgrp = blockIdx.x & 63;
  int w = threadIdx.x >> 6, l = threadIdx.x & 63;
  int s = (sgrp << 6) + l;
  int qi = (b << 12) + s;
  float q0 = qx[qi], q1 = qy[qi], q2 = qz[qi];
  // xx2 = (q0^2 + q1^2) + q2^2 : muls separate, sequential adds (no fma)
  float sq0 = q0 * q0; OPAQUE(sq0);
  float sq1 = q1 * q1; OPAQUE(sq1);
  float sq2 = q2 * q2; OPAQUE(sq2);
  float qq = (sq0 + sq1) + sq2;
  const float* xs = x + (size_t)b * 5 * P;
  const float* ys = xs + P;
  const float* zs = xs + 2 * P;
  int base = w * 4096;
  const float4* xs4 = (const float4*)(xs + base);
  const float4* ys4 = (const float4*)(ys + base);
  const float4* zs4 = (const float4*)(zs + base);

  u64 L[16];
#pragma unroll
  for (int k = 0; k < 16; ++k) L[k] = ~0ULL;
  u32 worst_dk = 0xFFFFFFFFu;
  int cnt = 0;
  u64* bufp = buf[threadIdx.x];

  auto drain = [&]() {
    while (__any(cnt > 0)) {
      if (cnt > 0) {
        --cnt;
        u64 key = bufp[cnt];
        if (key < L[15]) insert16(L, key);
      }
    }
    worst_dk = (u32)(L[15] >> 32);
  };

  for (int j = 0; j < 1024; ++j) {
    float4 cx = xs4[j];
    float4 cy = ys4[j];
    float4 cz = zs4[j];
    float cxa[4] = {cx.x, cx.y, cx.z, cx.w};
    float cya[4] = {cy.x, cy.y, cy.z, cy.w};
    float cza[4] = {cz.x, cz.y, cz.z, cz.w};
#pragma unroll
    for (int t = 0; t < 4; ++t) {
      // xx = (x0^2 + x1^2) + x2^2 (muls separate, no fma in adds)
      float t0 = cxa[t] * cxa[t]; OPAQUE(t0);
      float t1 = cya[t] * cya[t]; OPAQUE(t1);
      float t2 = cza[t] * cza[t]; OPAQUE(t2);
      float xxp = (t0 + t1) + t2;
      // ip = fma(x2,q2, fma(x1,q1, round(x0*q0)))  (GEMM K=3 fma chain)
      float ip = __builtin_fmaf(cza[t], q2,
                                __builtin_fmaf(cya[t], q1, cxa[t] * q0));
      float inner = -2.0f * ip; OPAQUE(inner);
      float pd = (-xxp - inner) - qq;
      u32 dk = pd_to_dk(pd);
      // <=: equal-pd candidate with smaller index must be able to displace
      // the current 16th (top_k tie-breaks by lowest index).
      if (dk <= worst_dk) {
        bufp[cnt] = ((u64)dk << 32) | (u32)(base + (j << 2) + t);
        ++cnt;
      }
    }
    if (__any(cnt >= CAP - 4)) drain();
  }
  drain();

#pragma unroll
  for (int k = 0; k < 16; ++k) lists[w][l][k] = L[k];
  __syncthreads();

  u64* mgf = &buf[0][0];  // [64][16] merged keys, aliases buf (scan finished)
  if (w == 0) {
    int p0 = 0, p1 = 0, p2 = 0, p3 = 0;
    u64 h0 = lists[0][l][0], h1 = lists[1][l][0];
    u64 h2 = lists[2][l][0], h3 = lists[3][l][0];
    for (int k = 0; k < 16; ++k) {
      u64 m01 = (h0 < h1) ? h0 : h1;
      u64 m23 = (h2 < h3) ? h2 : h3;
      u64 m = (m01 < m23) ? m01 : m23;
      mgf[l * 16 + k] = m;
      if (m == h0)      { ++p0; h0 = (p0 < 16) ? lists[0][l][p0] : ~0ULL; }
      else if (m == h1) { ++p1; h1 = (p1 < 16) ? lists[1][l][p1] : ~0ULL; }
      else if (m == h2) { ++p2; h2 = (p2 < 16) ? lists[2][l][p2] : ~0ULL; }
      else              { ++p3; h3 = (p3 < 16) ? lists[3][l][p3] : ~0ULL; }
    }
  }
  __syncthreads();

  // epilogue: thread t -> (query row, k-quartet); coalesced float4 stores
  int qrow = threadIdx.x >> 2;
  int g = threadIdx.x & 3;
  int sOut = (sgrp << 6) + qrow;
  u32 i0 = (u32)mgf[qrow * 16 + g * 4 + 0];
  u32 i1 = (u32)mgf[qrow * 16 + g * 4 + 1];
  u32 i2 = (u32)mgf[qrow * 16 + g * 4 + 2];
  u32 i3 = (u32)mgf[qrow * 16 + g * 4 + 3];
#pragma unroll
  for (int c = 0; c < 5; ++c) {
    const float* xc = x + (size_t)(b * 5 + c) * P;
    float4 v;
    v.x = xc[i0]; v.y = xc[i1]; v.z = xc[i2]; v.w = xc[i3];
    float* op = out + (((size_t)(b * 5 + c) * S + sOut) << 4) + (g << 2);
    *(float4*)op = v;
  }
}

extern "C" void kernel_launch(void* const* d_in, const int* in_sizes, int n_in,
                              void* d_out, int out_size, void* d_ws, size_t ws_size,
                              hipStream_t stream) {
  const float* x = (const float*)d_in[0];
  float* out = (float*)d_out;
  float* mm = (float*)d_ws;                       // 32 floats
  float* qx = (float*)((char*)d_ws + 1024);       // [NB*S]
  float* qy = qx + NB * S;
  float* qz = qy + NB * S;

  kminmax<<<NB, 256, 0, stream>>>(x, mm);
  kidx1<<<NB * 64, 256, 0, stream>>>(x, mm, qx, qy, qz);
  kidx2<<<NB * 64, 256, 0, stream>>>(x, qx, qy, qz, out);
}

// Round 6
// 670.296 us; speedup vs baseline: 1.1987x; 1.1987x over previous
//
#include <hip/hip_runtime.h>

#define P 16384
#define S 4096
#define NB 8
#define CAP 12

typedef unsigned long long u64;
typedef unsigned int u32;

// Opaque identity: forces separate rounding, blocks fma contraction across it.
#define OPAQUE(x) __asm__("" : "+v"(x))

// pd (f32, ref formula) -> u32 key monotone DESCENDING in pd; (dk<<32)|idx in
// ascending u64 order reproduces jax.lax.top_k (largest pd, ties->lower idx).
__device__ __forceinline__ u32 pd_to_dk(float pd) {
  pd = pd + 0.0f;                        // canonicalize -0 -> +0
  u32 b = __float_as_uint(pd);
  u32 s = (u32)((int)b >> 31);
  return b ^ (~(s | 0x80000000u));       // neg: b ; non-neg: b ^ 0x7FFFFFFF
}
__device__ __forceinline__ float dk_to_pd(u32 d) {
  u32 pb = (d & 0x80000000u) ? d : (d ^ 0x7FFFFFFFu);
  return __uint_as_float(pb);            // sentinel 0xFF800000 -> -inf
}

__device__ __forceinline__ void insert16(u64 (&L)[16], u64 key) {
#pragma unroll
  for (int j = 15; j >= 1; --j) {
    u64 a = (L[j - 1] > key) ? L[j - 1] : key;
    L[j] = (L[j] > key) ? a : L[j];
  }
  L[0] = (L[0] > key) ? key : L[0];
}

// ---------------- Kernel A: per-batch min/max of channels 0,1 ----------------
__global__ void kminmax(const float* __restrict__ x, float* __restrict__ mm) {
  int b = blockIdx.x;
  int tid = threadIdx.x;
  const float* x0 = x + (size_t)b * 5 * P;
  const float* x1 = x0 + P;
  float mn0 = __builtin_inff(), mx0 = -__builtin_inff();
  float mn1 = __builtin_inff(), mx1 = -__builtin_inff();
  for (int i = tid; i < P; i += 256) {
    float a = x0[i];
    mn0 = fminf(mn0, a); mx0 = fmaxf(mx0, a);
    float c = x1[i];
    mn1 = fminf(mn1, c); mx1 = fmaxf(mx1, c);
  }
  __shared__ float s0[256], s1[256], s2[256], s3[256];
  s0[tid] = mn0; s1[tid] = mx0; s2[tid] = mn1; s3[tid] = mx1;
  __syncthreads();
  for (int off = 128; off > 0; off >>= 1) {
    if (tid < off) {
      s0[tid] = fminf(s0[tid], s0[tid + off]);
      s1[tid] = fmaxf(s1[tid], s1[tid + off]);
      s2[tid] = fminf(s2[tid], s2[tid + off]);
      s3[tid] = fmaxf(s3[tid], s3[tid + off]);
    }
    __syncthreads();
  }
  if (tid == 0) {
    mm[b * 4 + 0] = s0[0];
    mm[b * 4 + 1] = s1[0];
    mm[b * 4 + 2] = s2[0];
    mm[b * 4 + 3] = s3[0];
  }
}

// ---------------- Kernel P: precompute xx (2D and 3D), exact ref roundings --
__global__ void kprep(const float* __restrict__ x, float* __restrict__ xx2d,
                      float* __restrict__ xx3d) {
#pragma clang fp contract(off)
  int gid = blockIdx.x * 256 + threadIdx.x;   // 0 .. NB*P-1
  int b = gid >> 14;
  int i = gid & (P - 1);
  const float* xs = x + (size_t)b * 5 * P;
  float x0 = xs[i], x1 = xs[P + i], x2 = xs[2 * P + i];
  float t0 = x0 * x0; OPAQUE(t0);
  float t1 = x1 * x1; OPAQUE(t1);
  float t2 = x2 * x2; OPAQUE(t2);
  float s2 = t0 + t1;
  xx2d[gid] = s2;
  xx3d[gid] = s2 + t2;
}

// ---------------- Kernel B: 1-NN in 2D, per-half best (float compare) -------
// grid NB*64*2: (b, sgrp, cand-half); 4 waves scan 2048 cands each.
__global__ __launch_bounds__(256) void kidx1(const float* __restrict__ x,
                                             const float* __restrict__ mm,
                                             const float* __restrict__ xx2d,
                                             u64* __restrict__ bests) {
#pragma clang fp contract(off)
  int blk = blockIdx.x;
  int b = blk >> 7;
  int sgrp = (blk >> 1) & 63;
  int half = blk & 1;
  int w = threadIdx.x >> 6, l = threadIdx.x & 63;
  const float* xs = x + (size_t)b * 5 * P;
  const float* ys = xs + P;
  float mn0 = mm[b * 4 + 0], mx0 = mm[b * 4 + 1];
  float mn1 = mm[b * 4 + 2], mx1 = mm[b * 4 + 3];
  float m0 = (float)l * (1.0f / 64.0f);
  float m1 = (float)sgrp * (1.0f / 64.0f);
  float d0 = mx0 - mn0, d1 = mx1 - mn1;
  float p0 = m0 * d0; OPAQUE(p0);
  float q0 = p0 + mn0;
  float p1 = m1 * d1; OPAQUE(p1);
  float q1 = p1 + mn1;
  float sq0 = q0 * q0; OPAQUE(sq0);
  float sq1 = q1 * q1; OPAQUE(sq1);
  float qq = sq0 + sq1;

  int base = half * 8192 + w * 2048;
  const float4* xs4 = (const float4*)(xs + base);
  const float4* ys4 = (const float4*)(ys + base);
  const float4* ws4 = (const float4*)(xx2d + b * P + base);
  float best_pd = -__builtin_inff();
  u32 best_idx = 0;
  for (int j = 0; j < 512; ++j) {
    float4 cx = xs4[j];
    float4 cy = ys4[j];
    float4 cw = ws4[j];
    float cxa[4] = {cx.x, cx.y, cx.z, cx.w};
    float cya[4] = {cy.x, cy.y, cy.z, cy.w};
    float cwa[4] = {cw.x, cw.y, cw.z, cw.w};
#pragma unroll
    for (int t = 0; t < 4; ++t) {
      // ip = fma(x1,q1, round(x0*q0)); pd = fma(2,ip,-xx) - qq
      // (fma(2,ip,-xx) == (-xx) - (-2*ip) bitwise: -2*ip is exact)
      float ip = __builtin_fmaf(cya[t], q1, cxa[t] * q0);
      float a  = __builtin_fmaf(2.0f, ip, -cwa[t]);
      float pd = a - qq;
      bool bt = pd > best_pd;   // strict: ties keep earlier (lower idx)
      best_pd  = bt ? pd : best_pd;
      best_idx = bt ? (u32)(base + (j << 2) + t) : best_idx;
    }
  }
  u64 key = ((u64)pd_to_dk(best_pd) << 32) | best_idx;
  __shared__ u64 kb[4][64];
  kb[w][l] = key;
  __syncthreads();
  if (threadIdx.x < 64) {
    u64 m = kb[0][l];
    u64 t1 = kb[1][l]; m = (t1 < m) ? t1 : m;
    u64 t2 = kb[2][l]; m = (t2 < m) ? t2 : m;
    u64 t3 = kb[3][l]; m = (t3 < m) ? t3 : m;
    bests[(size_t)(((b * 64 + sgrp) * 2 + half) * 64 + l)] = m;
  }
}

// ---------------- Kernel Q: merge halves, gather query xyz ------------------
__global__ void kq(const float* __restrict__ x, const u64* __restrict__ bests,
                   float* __restrict__ qx, float* __restrict__ qy,
                   float* __restrict__ qz) {
  int qi = blockIdx.x * 256 + threadIdx.x;   // 0..NB*S-1
  int b = qi >> 12;
  int s = qi & 4095;
  int sgrp = s >> 6, l = s & 63;
  size_t o = (size_t)(((b * 64 + sgrp) * 2) * 64 + l);
  u64 a = bests[o];
  u64 c = bests[o + 64];
  u64 m = (c < a) ? c : a;
  u32 idx = (u32)m;
  const float* xs = x + (size_t)b * 5 * P;
  qx[qi] = xs[idx];
  qy[qi] = xs[P + idx];
  qz[qi] = xs[2 * P + idx];
}

// ---------------- Kernel C: 16-NN in 3D (float thr, precomp xx) + gather ----
__global__ __launch_bounds__(256) void kidx2(const float* __restrict__ x,
                                             const float* __restrict__ xx3d,
                                             const float* __restrict__ qx,
                                             const float* __restrict__ qy,
                                             const float* __restrict__ qz,
                                             float* __restrict__ out) {
#pragma clang fp contract(off)
  __shared__ u64 lists[4][64][16];   // 32 KB
  __shared__ u64 buf[256][CAP];      // 24 KB (reused post-scan for merged keys)
  int b = blockIdx.x >> 6, sgrp = blockIdx.x & 63;
  int w = threadIdx.x >> 6, l = threadIdx.x & 63;
  int s = (sgrp << 6) + l;
  int qi = (b << 12) + s;
  float q0 = qx[qi], q1 = qy[qi], q2 = qz[qi];
  float sq0 = q0 * q0; OPAQUE(sq0);
  float sq1 = q1 * q1; OPAQUE(sq1);
  float sq2 = q2 * q2; OPAQUE(sq2);
  float qq = (sq0 + sq1) + sq2;
  const float* xs = x + (size_t)b * 5 * P;
  const float* ys = xs + P;
  const float* zs = xs + 2 * P;
  int base = w * 4096;
  const float4* xs4 = (const float4*)(xs + base);
  const float4* ys4 = (const float4*)(ys + base);
  const float4* zs4 = (const float4*)(zs + base);
  const float4* ws4 = (const float4*)(xx3d + b * P + base);

  u64 L[16];
#pragma unroll
  for (int k = 0; k < 16; ++k) L[k] = 0xFF800000FFFFFFFFull;  // dk=-inf bits
  float thr = -__builtin_inff();   // accept pd >= thr (pd of current 16th)
  int cnt = 0;
  u64* bufp = buf[threadIdx.x];

  auto drain = [&]() {
    while (__any(cnt > 0)) {
      if (cnt > 0) {
        --cnt;
        u64 e = bufp[cnt];
        u64 key = ((u64)pd_to_dk(__uint_as_float((u32)(e >> 32))) << 32) | (u32)e;
        if (key < L[15]) insert16(L, key);
      }
    }
    thr = dk_to_pd((u32)(L[15] >> 32));
  };

  for (int j = 0; j < 1024; ++j) {
    float4 cx = xs4[j];
    float4 cy = ys4[j];
    float4 cz = zs4[j];
    float4 cw = ws4[j];
    float cxa[4] = {cx.x, cx.y, cx.z, cx.w};
    float cya[4] = {cy.x, cy.y, cy.z, cy.w};
    float cza[4] = {cz.x, cz.y, cz.z, cz.w};
    float cwa[4] = {cw.x, cw.y, cw.z, cw.w};
#pragma unroll
    for (int t = 0; t < 4; ++t) {
      // ip = fma(x2,q2, fma(x1,q1, round(x0*q0)))
      // pd = fma(2,ip,-xx) - qq   (bitwise == ((-xx)-(-2*ip)) - qq)
      float ip = __builtin_fmaf(cza[t], q2,
                                __builtin_fmaf(cya[t], q1, cxa[t] * q0));
      float a  = __builtin_fmaf(2.0f, ip, -cwa[t]);
      float pd = a - qq;
      // >=: equal-pd candidate (incl. +/-0) must survive for idx tie-break.
      if (pd >= thr) {
        bufp[cnt] = ((u64)__float_as_uint(pd) << 32) | (u32)(base + (j << 2) + t);
        ++cnt;
      }
    }
    if (__any(cnt >= CAP - 4)) drain();
  }
  drain();

#pragma unroll
  for (int k = 0; k < 16; ++k) lists[w][l][k] = L[k];
  __syncthreads();

  u64* mgf = &buf[0][0];  // [64][16] merged keys, aliases buf (scan finished)
  if (w == 0) {
    int p0 = 0, p1 = 0, p2 = 0, p3 = 0;
    u64 h0 = lists[0][l][0], h1 = lists[1][l][0];
    u64 h2 = lists[2][l][0], h3 = lists[3][l][0];
    for (int k = 0; k < 16; ++k) {
      u64 m01 = (h0 < h1) ? h0 : h1;
      u64 m23 = (h2 < h3) ? h2 : h3;
      u64 m = (m01 < m23) ? m01 : m23;
      mgf[l * 16 + k] = m;
      if (m == h0)      { ++p0; h0 = (p0 < 16) ? lists[0][l][p0] : ~0ULL; }
      else if (m == h1) { ++p1; h1 = (p1 < 16) ? lists[1][l][p1] : ~0ULL; }
      else if (m == h2) { ++p2; h2 = (p2 < 16) ? lists[2][l][p2] : ~0ULL; }
      else              { ++p3; h3 = (p3 < 16) ? lists[3][l][p3] : ~0ULL; }
    }
  }
  __syncthreads();

  int qrow = threadIdx.x >> 2;
  int g = threadIdx.x & 3;
  int sOut = (sgrp << 6) + qrow;
  u32 i0 = (u32)mgf[qrow * 16 + g * 4 + 0];
  u32 i1 = (u32)mgf[qrow * 16 + g * 4 + 1];
  u32 i2 = (u32)mgf[qrow * 16 + g * 4 + 2];
  u32 i3 = (u32)mgf[qrow * 16 + g * 4 + 3];
#pragma unroll
  for (int c = 0; c < 5; ++c) {
    const float* xc = x + (size_t)(b * 5 + c) * P;
    float4 v;
    v.x = xc[i0]; v.y = xc[i1]; v.z = xc[i2]; v.w = xc[i3];
    float* op = out + (((size_t)(b * 5 + c) * S + sOut) << 4) + (g << 2);
    *(float4*)op = v;
  }
}

extern "C" void kernel_launch(void* const* d_in, const int* in_sizes, int n_in,
                              void* d_out, int out_size, void* d_ws, size_t ws_size,
                              hipStream_t stream) {
  const float* x = (const float*)d_in[0];
  float* out = (float*)d_out;
  char* ws = (char*)d_ws;
  float* mm   = (float*)ws;                       // 128 B (pad to 1 KB)
  float* xx2d = (float*)(ws + 1024);              // NB*P f32 = 512 KB
  float* xx3d = (float*)(ws + 1024 + 524288);     // 512 KB
  u64*   bests= (u64*)  (ws + 1024 + 2 * 524288); // NB*64*2*64 u64 = 512 KB
  float* qx   = (float*)(ws + 1024 + 3 * 524288); // NB*S f32 = 128 KB
  float* qy   = qx + NB * S;
  float* qz   = qy + NB * S;

  kminmax<<<NB, 256, 0, stream>>>(x, mm);
  kprep<<<NB * P / 256, 256, 0, stream>>>(x, xx2d, xx3d);
  kidx1<<<NB * 128, 256, 0, stream>>>(x, mm, xx2d, bests);
  kq<<<NB * S / 256, 256, 0, stream>>>(x, bests, qx, qy, qz);
  kidx2<<<NB * 64, 256, 0, stream>>>(x, xx3d, qx, qy, qz, out);
}

// Round 7
// 621.514 us; speedup vs baseline: 1.2928x; 1.0785x over previous
//
#include <hip/hip_runtime.h>

#define P 16384
#define S 4096
#define NB 8
#define CAP 16

typedef unsigned long long u64;
typedef unsigned int u32;

// Opaque identity: forces separate rounding, blocks fma contraction across it.
#define OPAQUE(x) __asm__("" : "+v"(x))

// pd (f32, ref formula) -> u32 key monotone DESCENDING in pd; (dk<<32)|idx in
// ascending u64 order reproduces jax.lax.top_k (largest pd, ties->lower idx).
__device__ __forceinline__ u32 pd_to_dk(float pd) {
  pd = pd + 0.0f;                        // canonicalize -0 -> +0
  u32 b = __float_as_uint(pd);
  u32 s = (u32)((int)b >> 31);
  return b ^ (~(s | 0x80000000u));       // neg: b ; non-neg: b ^ 0x7FFFFFFF
}
__device__ __forceinline__ float dk_to_pd(u32 d) {
  u32 pb = (d & 0x80000000u) ? d : (d ^ 0x7FFFFFFFu);
  return __uint_as_float(pb);            // sentinel 0xFF800000 -> -inf
}
// 2-ulp step toward -inf; conservative lower bound for threshold transform.
__device__ __forceinline__ float prev2(float v) {
  u32 b = __float_as_uint(v);
  if ((b & 0x7F800000u) == 0x7F800000u) return v;   // +-inf: keep
  if (v > 0.0f) b -= 2;
  else if (v < 0.0f) b += 2;
  else return -1e-30f;
  return __uint_as_float(b);
}

__device__ __forceinline__ void insert16(u64 (&L)[16], u64 key) {
#pragma unroll
  for (int j = 15; j >= 1; --j) {
    u64 a = (L[j - 1] > key) ? L[j - 1] : key;
    L[j] = (L[j] > key) ? a : L[j];
  }
  L[0] = (L[0] > key) ? key : L[0];
}

// ---------------- Kernel A: per-batch min/max of channels 0,1 ----------------
__global__ void kminmax(const float* __restrict__ x, float* __restrict__ mm) {
  int b = blockIdx.x;
  int tid = threadIdx.x;
  const float* x0 = x + (size_t)b * 5 * P;
  const float* x1 = x0 + P;
  float mn0 = __builtin_inff(), mx0 = -__builtin_inff();
  float mn1 = __builtin_inff(), mx1 = -__builtin_inff();
  for (int i = tid; i < P; i += 256) {
    float a = x0[i];
    mn0 = fminf(mn0, a); mx0 = fmaxf(mx0, a);
    float c = x1[i];
    mn1 = fminf(mn1, c); mx1 = fmaxf(mx1, c);
  }
  __shared__ float s0[256], s1[256], s2[256], s3[256];
  s0[tid] = mn0; s1[tid] = mx0; s2[tid] = mn1; s3[tid] = mx1;
  __syncthreads();
  for (int off = 128; off > 0; off >>= 1) {
    if (tid < off) {
      s0[tid] = fminf(s0[tid], s0[tid + off]);
      s1[tid] = fmaxf(s1[tid], s1[tid + off]);
      s2[tid] = fminf(s2[tid], s2[tid + off]);
      s3[tid] = fmaxf(s3[tid], s3[tid + off]);
    }
    __syncthreads();
  }
  if (tid == 0) {
    mm[b * 4 + 0] = s0[0];
    mm[b * 4 + 1] = s1[0];
    mm[b * 4 + 2] = s2[0];
    mm[b * 4 + 3] = s3[0];
  }
}

// ---------------- Kernel P: precompute xx (2D and 3D), exact ref roundings --
__global__ void kprep(const float* __restrict__ x, float* __restrict__ xx2d,
                      float* __restrict__ xx3d) {
#pragma clang fp contract(off)
  int gid = blockIdx.x * 256 + threadIdx.x;   // 0 .. NB*P-1
  int b = gid >> 14;
  int i = gid & (P - 1);
  const float* xs = x + (size_t)b * 5 * P;
  float x0 = xs[i], x1 = xs[P + i], x2 = xs[2 * P + i];
  float t0 = x0 * x0; OPAQUE(t0);
  float t1 = x1 * x1; OPAQUE(t1);
  float t2 = x2 * x2; OPAQUE(t2);
  float s2 = t0 + t1;
  xx2d[gid] = s2;
  xx3d[gid] = s2 + t2;
}

// ---------------- Kernel B: 1-NN in 2D, 4-way candidate split ---------------
// grid NB*64*4: (b, sgrp, quarter); 4 waves scan 1024 cands each.
__global__ __launch_bounds__(256) void kidx1(const float* __restrict__ x,
                                             const float* __restrict__ mm,
                                             const float* __restrict__ xx2d,
                                             u64* __restrict__ bests1) {
#pragma clang fp contract(off)
  int blk = blockIdx.x;
  int b = blk >> 8;
  int sgrp = (blk >> 2) & 63;
  int qtr = blk & 3;
  int w = threadIdx.x >> 6, l = threadIdx.x & 63;
  const float* xs = x + (size_t)b * 5 * P;
  const float* ys = xs + P;
  float mn0 = mm[b * 4 + 0], mx0 = mm[b * 4 + 1];
  float mn1 = mm[b * 4 + 2], mx1 = mm[b * 4 + 3];
  float m0 = (float)l * (1.0f / 64.0f);
  float m1 = (float)sgrp * (1.0f / 64.0f);
  float d0 = mx0 - mn0, d1 = mx1 - mn1;
  float p0 = m0 * d0; OPAQUE(p0);
  float q0 = p0 + mn0;
  float p1 = m1 * d1; OPAQUE(p1);
  float q1 = p1 + mn1;
  float sq0 = q0 * q0; OPAQUE(sq0);
  float sq1 = q1 * q1; OPAQUE(sq1);
  float qq = sq0 + sq1;

  int base = qtr * 4096 + w * 1024;
  const float4* xs4 = (const float4*)(xs + base);
  const float4* ys4 = (const float4*)(ys + base);
  const float4* ws4 = (const float4*)(xx2d + b * P + base);
  float best_pd = -__builtin_inff();
  u32 best_idx = 0;
  for (int j = 0; j < 256; ++j) {
    float4 cx = xs4[j];
    float4 cy = ys4[j];
    float4 cw = ws4[j];
    float cxa[4] = {cx.x, cx.y, cx.z, cx.w};
    float cya[4] = {cy.x, cy.y, cy.z, cy.w};
    float cwa[4] = {cw.x, cw.y, cw.z, cw.w};
#pragma unroll
    for (int t = 0; t < 4; ++t) {
      // ip = fma(x1,q1, round(x0*q0)); pd = fma(2,ip,-xx) - qq
      float ip = __builtin_fmaf(cya[t], q1, cxa[t] * q0);
      float a  = __builtin_fmaf(2.0f, ip, -cwa[t]);
      float pd = a - qq;
      bool bt = pd > best_pd;   // strict: ties keep earlier (lower idx)
      best_pd  = bt ? pd : best_pd;
      best_idx = bt ? (u32)(base + (j << 2) + t) : best_idx;
    }
  }
  u64 key = ((u64)pd_to_dk(best_pd) << 32) | best_idx;
  __shared__ u64 kb[4][64];
  kb[w][l] = key;
  __syncthreads();
  if (threadIdx.x < 64) {
    u64 m = kb[0][l];
    u64 t1 = kb[1][l]; m = (t1 < m) ? t1 : m;
    u64 t2 = kb[2][l]; m = (t2 < m) ? t2 : m;
    u64 t3 = kb[3][l]; m = (t3 < m) ? t3 : m;
    bests1[((size_t)((b * 64 + sgrp) * 4 + qtr) << 6) + l] = m;
  }
}

// ---------------- Kernel Q: merge quarters, gather query xyz ----------------
__global__ void kq(const float* __restrict__ x, const u64* __restrict__ bests1,
                   float* __restrict__ qx, float* __restrict__ qy,
                   float* __restrict__ qz) {
  int qi = blockIdx.x * 256 + threadIdx.x;   // 0..NB*S-1
  int b = qi >> 12;
  int s = qi & 4095;
  int sgrp = s >> 6, l = s & 63;
  size_t o = ((size_t)((b * 64 + sgrp) * 4) << 6) + l;
  u64 m = bests1[o];
  u64 t;
  t = bests1[o + 64];  m = (t < m) ? t : m;
  t = bests1[o + 128]; m = (t < m) ? t : m;
  t = bests1[o + 192]; m = (t < m) ? t : m;
  u32 idx = (u32)m;
  const float* xs = x + (size_t)b * 5 * P;
  qx[qi] = xs[idx];
  qy[qi] = xs[P + idx];
  qz[qi] = xs[2 * P + idx];
}

// ---------------- Kernel C: 16-NN in 3D, 512 threads / 8 wave-chunks --------
__global__ __launch_bounds__(512) void kidx2(const float* __restrict__ x,
                                             const float* __restrict__ xx3d,
                                             const float* __restrict__ qx,
                                             const float* __restrict__ qy,
                                             const float* __restrict__ qz,
                                             float* __restrict__ out) {
#pragma clang fp contract(off)
  __shared__ u64 buf[512][CAP + 1];   // 69.6 KB; +1 pad breaks bank aliasing
  __shared__ u64 mgf[64][17];         // 8.7 KB merged lists
  int b = blockIdx.x >> 6, sgrp = blockIdx.x & 63;
  int w = threadIdx.x >> 6, l = threadIdx.x & 63;
  int s = (sgrp << 6) + l;
  int qi = (b << 12) + s;
  float q0 = qx[qi], q1 = qy[qi], q2 = qz[qi];
  float sq0 = q0 * q0; OPAQUE(sq0);
  float sq1 = q1 * q1; OPAQUE(sq1);
  float sq2 = q2 * q2; OPAQUE(sq2);
  float qq = (sq0 + sq1) + sq2;
  const float* xs = x + (size_t)b * 5 * P;
  const float* ys = xs + P;
  const float* zs = xs + 2 * P;
  int base = w * 2048;
  const float4* xs4 = (const float4*)(xs + base);
  const float4* ys4 = (const float4*)(ys + base);
  const float4* zs4 = (const float4*)(zs + base);
  const float4* ws4 = (const float4*)(xx3d + b * P + base);

  u64 L[16];
#pragma unroll
  for (int k = 0; k < 16; ++k) L[k] = 0xFF800000FFFFFFFFull;  // dk(-inf)|idx
  // Accept test in a-space: a = fma(2,ip,-xx); pd = a - qq. Monotone in a, so
  // accept iff a >= thrA with thrA = prev2(thr_pd + qq) (2 ulp conservative;
  // over-accepts are filtered exactly in the drain).
  float thrA = -__builtin_inff();
  int cnt = 0;
  u64* bufp = buf[threadIdx.x];

  auto drain = [&]() {
    while (__any(cnt > 0)) {
      if (cnt > 0) {
        --cnt;
        u64 e = bufp[cnt];
        float pd = __uint_as_float((u32)(e >> 32)) - qq;  // exact ref rounding
        u64 key = ((u64)pd_to_dk(pd) << 32) | (u32)e;
        if (key < L[15]) insert16(L, key);
      }
    }
    float tp = dk_to_pd((u32)(L[15] >> 32));
    thrA = prev2(tp + qq);     // -inf stays -inf
  };

  for (int j = 0; j < 512; ++j) {
    float4 cx = xs4[j];
    float4 cy = ys4[j];
    float4 cz = zs4[j];
    float4 cw = ws4[j];
    float cxa[4] = {cx.x, cx.y, cx.z, cx.w};
    float cya[4] = {cy.x, cy.y, cy.z, cy.w};
    float cza[4] = {cz.x, cz.y, cz.z, cz.w};
    float cwa[4] = {cw.x, cw.y, cw.z, cw.w};
#pragma unroll
    for (int t = 0; t < 4; ++t) {
      float ip = __builtin_fmaf(cza[t], q2,
                                __builtin_fmaf(cya[t], q1, cxa[t] * q0));
      float a  = __builtin_fmaf(2.0f, ip, -cwa[t]);
      if (a >= thrA) {
        bufp[cnt] = ((u64)__float_as_uint(a) << 32) | (u32)(base + (j << 2) + t);
        ++cnt;
      }
    }
    if (__any(cnt >= CAP - 4)) drain();
  }
  drain();

  // lists -> buf rows (cnt==0 everywhere; rows are free, 16 <= CAP+1)
#pragma unroll
  for (int k = 0; k < 16; ++k) bufp[k] = L[k];
  __syncthreads();

  if (w == 0) {
    // 8-way lazy merge for query l: lists live at rows {wv*64+l}
    int p0 = 0, p1 = 0, p2 = 0, p3 = 0, p4 = 0, p5 = 0, p6 = 0, p7 = 0;
    u64 h0 = buf[l][0],        h1 = buf[64 + l][0];
    u64 h2 = buf[128 + l][0],  h3 = buf[192 + l][0];
    u64 h4 = buf[256 + l][0],  h5 = buf[320 + l][0];
    u64 h6 = buf[384 + l][0],  h7 = buf[448 + l][0];
#define ADV(i) { ++p##i; h##i = (p##i < 16) ? buf[i * 64 + l][p##i] : ~0ULL; }
    for (int k = 0; k < 16; ++k) {
      u64 m01 = (h0 < h1) ? h0 : h1;
      u64 m23 = (h2 < h3) ? h2 : h3;
      u64 m45 = (h4 < h5) ? h4 : h5;
      u64 m67 = (h6 < h7) ? h6 : h7;
      u64 ma = (m01 < m23) ? m01 : m23;
      u64 mb = (m45 < m67) ? m45 : m67;
      u64 m = (ma < mb) ? ma : mb;
      mgf[l][k] = m;
      if      (m == h0) ADV(0)
      else if (m == h1) ADV(1)
      else if (m == h2) ADV(2)
      else if (m == h3) ADV(3)
      else if (m == h4) ADV(4)
      else if (m == h5) ADV(5)
      else if (m == h6) ADV(6)
      else              ADV(7)
    }
#undef ADV
  }
  __syncthreads();

  // epilogue: thread -> (query row, k-pair); coalesced float2 stores
  int qrow = threadIdx.x >> 3;
  int g = threadIdx.x & 7;
  int sOut = (sgrp << 6) + qrow;
  u32 i0 = (u32)mgf[qrow][g * 2 + 0];
  u32 i1 = (u32)mgf[qrow][g * 2 + 1];
#pragma unroll
  for (int c = 0; c < 5; ++c) {
    const float* xc = x + (size_t)(b * 5 + c) * P;
    float2 v;
    v.x = xc[i0]; v.y = xc[i1];
    float* op = out + (((size_t)(b * 5 + c) * S + sOut) << 4) + (g << 1);
    *(float2*)op = v;
  }
}

extern "C" void kernel_launch(void* const* d_in, const int* in_sizes, int n_in,
                              void* d_out, int out_size, void* d_ws, size_t ws_size,
                              hipStream_t stream) {
  const float* x = (const float*)d_in[0];
  float* out = (float*)d_out;
  char* ws = (char*)d_ws;
  float* mm    = (float*)ws;                         // 1 KB
  float* xx2d  = (float*)(ws + 1024);                // 512 KB
  float* xx3d  = (float*)(ws + 1024 + 524288);       // 512 KB
  u64*   bests1= (u64*)  (ws + 1024 + 2 * 524288);   // NB*64*4*64 u64 = 1 MB
  float* qx    = (float*)(ws + 1024 + 2 * 524288 + 1048576);  // 128 KB
  float* qy    = qx + NB * S;
  float* qz    = qy + NB * S;

  kminmax<<<NB, 256, 0, stream>>>(x, mm);
  kprep<<<NB * P / 256, 256, 0, stream>>>(x, xx2d, xx3d);
  kidx1<<<NB * 256, 256, 0, stream>>>(x, mm, xx2d, bests1);
  kq<<<NB * S / 256, 256, 0, stream>>>(x, bests1, qx, qy, qz);
  kidx2<<<NB * 64, 512, 0, stream>>>(x, xx3d, qx, qy, qz, out);
}